// Round 15
// baseline (393.697 us; speedup 1.0000x reference)
//
#include <hip/hip_runtime.h>
#include <hip/hip_bf16.h>

#define ALPHA 0.01f

typedef __attribute__((ext_vector_type(8))) __bf16 bf16x8;
typedef __attribute__((ext_vector_type(4))) float f32x4;

#define BATCH 32
#define P1H 97
#define P1W 127
#define P2W 62
#define FLAT 186496
#define GK 512
#define NGK 365               // ceil(186496/512); last chunk = 128 (4 k-steps)
#define PSTRIDE1 16448        // 32*512 + 64 pad (floats)
#define PSTRIDE2 8256         // 32*256 + 64 pad
#define CONV1_BLOCKS 1540
#define LPITCH 264            // 1056 B rows: 16B-aligned uint4 writes

// LDS-only barrier: orders LDS traffic but lets pending GLOBAL loads float across.
#define BAR_LDS() asm volatile("s_waitcnt lgkmcnt(0)\n\ts_barrier" ::: "memory")

static __device__ __forceinline__ unsigned short f2bf(float x) {
  union { float f; unsigned u; } c; c.f = x;
  unsigned r = c.u + 0x7fffu + ((c.u >> 16) & 1u);
  return (unsigned short)(r >> 16);
}

static __device__ __forceinline__ unsigned pack2bf(float lo, float hi) {
  union { float f; unsigned u; } a, b;
  a.f = lo; b.f = hi;
  unsigned ra = (a.u + 0x7fffu + ((a.u >> 16) & 1u)) >> 16;
  unsigned rb = (b.u + 0x7fffu + ((b.u >> 16) & 1u)) & 0xffff0000u;
  return ra | rb;
}

// ------- conv1 (3x3x1->32) + ReLU + 2x2 maxpool -> p1 bf16 ; + w2 repack ----------
__global__ __launch_bounds__(256) void conv1_pool(const float* __restrict__ x,
    const float* __restrict__ w1, const float* __restrict__ b1,
    unsigned short* __restrict__ p1,
    const float* __restrict__ w2, unsigned short* __restrict__ bpack) {
  if (blockIdx.x >= CONV1_BLOCKS) {
    int o = (blockIdx.x - CONV1_BLOCKS) * 256 + threadIdx.x;
    if (o < 9 * 4 * 512) {
      int f = o >> 9;
      int within = o & 511;
      int lane = within >> 3, j = within & 7;
      int tap = f >> 2, nf = f & 3;
      int k = ((lane >> 4) << 3) + j;
      int n = nf * 16 + (lane & 15);
      bpack[o] = f2bf(w2[(tap * 32 + k) * 64 + n]);
    }
    return;
  }
  int pid = blockIdx.x * 256 + threadIdx.x;
  if (pid >= BATCH * P1H * P1W) return;
  int b = pid / (P1H * P1W);
  int rem = pid - b * (P1H * P1W);
  int ph = rem / P1W;
  int pw = rem - ph * P1W;
  const float* xb = x + ((b * 197 + 2 * ph) * 256 + 2 * pw);
  float in[4][4];
#pragma unroll
  for (int r = 0; r < 4; ++r) {
    float2 v0 = *reinterpret_cast<const float2*>(xb + r * 256);
    float2 v1 = *reinterpret_cast<const float2*>(xb + r * 256 + 2);
    in[r][0] = v0.x; in[r][1] = v0.y; in[r][2] = v1.x; in[r][3] = v1.y;
  }
  unsigned pk[16];
#pragma unroll
  for (int c = 0; c < 32; ++c) {
    float s00 = b1[c], s01 = s00, s10 = s00, s11 = s00;
#pragma unroll
    for (int ky = 0; ky < 3; ++ky)
#pragma unroll
      for (int kx = 0; kx < 3; ++kx) {
        float w = w1[(ky * 3 + kx) * 32 + c];
        s00 = fmaf(in[ky][kx], w, s00);
        s01 = fmaf(in[ky][kx + 1], w, s01);
        s10 = fmaf(in[ky + 1][kx], w, s10);
        s11 = fmaf(in[ky + 1][kx + 1], w, s11);
      }
    float m = fmaxf(fmaxf(s00, s01), fmaxf(s10, s11));
    m = fmaxf(m, 0.0f);
    unsigned short u = f2bf(m);
    if (c & 1) pk[c >> 1] |= ((unsigned)u) << 16;
    else pk[c >> 1] = (unsigned)u;
  }
  uint4* dst = reinterpret_cast<uint4*>(p1 + (size_t)pid * 32);
#pragma unroll
  for (int g = 0; g < 4; ++g)
    dst[g] = make_uint4(pk[g * 4], pk[g * 4 + 1], pk[g * 4 + 2], pk[g * 4 + 3]);
}

// ---------------- conv2 (3x3x32->64) MFMA + bias + ReLU + 2x2 maxpool -> h bf16 ----
__global__ __launch_bounds__(256) void conv2_pool(const unsigned short* __restrict__ p1,
    const unsigned short* __restrict__ bpack, const float* __restrict__ b2,
    unsigned short* __restrict__ hbf) {
  __shared__ alignas(16) unsigned char lds_buf[65536];
  int prow = blockIdx.x, b = blockIdx.y;
  int tid = threadIdx.x;
  int lane = tid & 63, wid = tid >> 6;
  {
    const uint4* src = reinterpret_cast<const uint4*>(bpack);
    uint4* dst = reinterpret_cast<uint4*>(lds_buf);
    for (int i = tid; i < 2304; i += 256) dst[i] = src[i];
  }
  __syncthreads();
  int row = lane & 15, kg = lane >> 4;
  int rowbase[4];
  int coff[4][3];
#pragma unroll
  for (int mf = 0; mf < 4; ++mf) {
    int m = wid * 64 + mf * 16 + row;
    int cro = m >> 7, cc = m & 127;
    rowbase[mf] = ((b * 97 + 2 * prow + cro) * 127) * 32 + kg * 8;
#pragma unroll
    for (int kx = 0; kx < 3; ++kx) {
      int ic = cc + kx; if (ic > 126) ic = 126;
      coff[mf][kx] = ic * 32;
    }
  }
  f32x4 acc[4][4];
#pragma unroll
  for (int i = 0; i < 4; ++i)
#pragma unroll
    for (int j = 0; j < 4; ++j) acc[i][j] = (f32x4){0.f, 0.f, 0.f, 0.f};

  const bf16x8* bl = reinterpret_cast<const bf16x8*>(lds_buf);
#pragma unroll
  for (int ky = 0; ky < 3; ++ky) {
#pragma unroll
    for (int kx = 0; kx < 3; ++kx) {
      int tap = ky * 3 + kx;
      bf16x8 a[4];
#pragma unroll
      for (int mf = 0; mf < 4; ++mf) {
        int addr = rowbase[mf] + ky * (127 * 32) + coff[mf][kx];
        a[mf] = *reinterpret_cast<const bf16x8*>(p1 + addr);
      }
      bf16x8 bf[4];
#pragma unroll
      for (int nf = 0; nf < 4; ++nf) bf[nf] = bl[(tap * 4 + nf) * 64 + lane];
#pragma unroll
      for (int nf = 0; nf < 4; ++nf)
#pragma unroll
        for (int mf = 0; mf < 4; ++mf)
          acc[mf][nf] = __builtin_amdgcn_mfma_f32_16x16x32_bf16(a[mf], bf[nf], acc[mf][nf], 0, 0, 0);
    }
  }
  __syncthreads();
  float* stage = reinterpret_cast<float*>(lds_buf);
#pragma unroll
  for (int mf = 0; mf < 4; ++mf)
#pragma unroll
    for (int nf = 0; nf < 4; ++nf) {
      int ch = nf * 16 + (lane & 15);
      float bias = b2[ch];
#pragma unroll
      for (int j = 0; j < 4; ++j) {
        int m = wid * 64 + mf * 16 + (lane >> 4) * 4 + j;
        float v = acc[mf][nf][j] + bias;
        stage[m * 64 + ch] = fmaxf(v, 0.f);
      }
    }
  __syncthreads();
  unsigned short* hb = hbf + (size_t)b * FLAT + prow * (P2W * 64);
  for (int o = tid; o < P2W * 64; o += 256) {
    int pw = o >> 6, ch = o & 63;
    int c0 = 2 * pw;
    float v = fmaxf(fmaxf(stage[c0 * 64 + ch], stage[(c0 + 1) * 64 + ch]),
                    fmaxf(stage[(128 + c0) * 64 + ch], stage[(129 + c0) * 64 + ch]));
    hb[o] = f2bf(v);
  }
}

// ------- MFMA big GEMM (r14 structure, UNCHANGED except blockIdx.z is ignored) ----
// INSTRUMENTATION: N=512 launch uses gridDim.z=3 to replicate identical work and
// push this dispatch above the harness-fill duration so rocprof top-5 shows its
// counters. Writes are deterministic and idempotent, so replays are safe.
template <int N, int CSTRIDE>
__global__ __launch_bounds__(256) void gemm_mfma(const float* __restrict__ W,
    const unsigned short* __restrict__ hbf, float* __restrict__ part) {
  __shared__ alignas(16) unsigned lds[16 * LPITCH];   // 16.5 KB
  int kc = blockIdx.y;
  int n0 = blockIdx.x * 256;
  int t = threadIdx.x, lane = t & 63, w = t >> 6;
  int k0 = kc * GK;
  int klen = FLAT - k0; if (klen > GK) klen = GK;
  int nsteps = klen >> 5;
  int cl = lane & 15, kg = lane >> 4;
  int mh = w & 1, nh = w >> 1;
  int kgl = kg & 1;

  const float* wsrc = W + (size_t)(k0 + w * 8) * N + n0 + lane * 4;
  unsigned* lwb = lds + (w * 4) * LPITCH + ((lane * 4) ^ ((w & 1) << 4));
  const unsigned short* ha = hbf + (size_t)(mh * 16 + cl) * FLAT + k0 + kg * 8;

  f32x4 acc[8];
#pragma unroll
  for (int f = 0; f < 8; ++f) acc[f] = (f32x4){0.f, 0.f, 0.f, 0.f};

  float4 st[8];
  bf16x8 a_cur, a_nxt;
  a_cur = *reinterpret_cast<const bf16x8*>(ha);
#pragma unroll
  for (int i = 0; i < 8; ++i)
    st[i] = *reinterpret_cast<const float4*>(wsrc + (size_t)i * N);

  for (int kt = 0; kt < nsteps; ++kt) {
    BAR_LDS();                       // A: prior readers done (no vmcnt drain)
#pragma unroll
    for (int ip = 0; ip < 4; ++ip) { // pack k-pairs of st(kt), write LDS
      float4 lo = st[2 * ip], hi = st[2 * ip + 1];
      *reinterpret_cast<uint4*>(lwb + ip * LPITCH) =
          make_uint4(pack2bf(lo.x, hi.x), pack2bf(lo.y, hi.y),
                     pack2bf(lo.z, hi.z), pack2bf(lo.w, hi.w));
    }
    if (kt + 1 < nsteps) {           // issue next step's W bursts immediately
      const float* ws = wsrc + (size_t)(kt + 1) * 32 * N;
#pragma unroll
      for (int i = 0; i < 8; ++i)
        st[i] = *reinterpret_cast<const float4*>(ws + (size_t)i * N);
    }
    BAR_LDS();                       // B: tile visible (no vmcnt drain)
    if (kt + 1 < nsteps)
      a_nxt = *reinterpret_cast<const bf16x8*>(ha + (kt + 1) * 32);
#pragma unroll
    for (int f = 0; f < 8; ++f) {
      int col = nh * 128 + ((f ^ kgl) * 16) + cl;   // swizzled storage addr
      union { unsigned u[4]; bf16x8 v; } bb;
#pragma unroll
      for (int p = 0; p < 4; ++p)
        bb.u[p] = lds[(kg * 4 + p) * LPITCH + col];
      acc[f] = __builtin_amdgcn_mfma_f32_16x16x32_bf16(a_cur, bb.v, acc[f], 0, 0, 0);
    }
    a_cur = a_nxt;
  }

  float* out = part + (size_t)kc * CSTRIDE + n0;
#pragma unroll
  for (int f = 0; f < 8; ++f)
#pragma unroll
    for (int j = 0; j < 4; ++j) {
      int m = mh * 16 + kg * 4 + j;
      int col = nh * 128 + f * 16 + cl;   // logical column (swizzle resolved)
      out[m * N + col] = acc[f][j];
    }
}

// ---------------- reduce split-K partials: 768 blocks, 8 threads/output ----------
__global__ __launch_bounds__(256) void reduce_big(const float* __restrict__ part1,
    const float* __restrict__ part2, const float* __restrict__ b_c1,
    const float* __restrict__ b_r1, float* __restrict__ y1, float* __restrict__ z1) {
  __shared__ float red[8][32];
  int b = blockIdx.x, t = threadIdx.x;
  int oo = t & 31, j = t >> 5;
  float s = 0.f;
  if (b < 512) {
    const float* p = part1 + b * 32 + oo;
    for (int c = j; c < NGK; c += 8) s += p[(size_t)c * PSTRIDE1];
    red[j][oo] = s;
    __syncthreads();
    if (t < 32) {
      float r = 0.f;
#pragma unroll
      for (int jj = 0; jj < 8; ++jj) r += red[jj][t];
      int o = b * 32 + t;
      r += b_c1[o & 511];
      y1[o] = r > 0.f ? r : ALPHA * r;
    }
  } else {
    const float* p = part2 + (b - 512) * 32 + oo;
    for (int c = j; c < NGK; c += 8) s += p[(size_t)c * PSTRIDE2];
    red[j][oo] = s;
    __syncthreads();
    if (t < 32) {
      float r = 0.f;
#pragma unroll
      for (int jj = 0; jj < 8; ++jj) r += red[jj][t];
      int u = (b - 512) * 32 + t;
      r += b_r1[u & 255];
      z1[u] = r > 0.f ? r : ALPHA * r;
    }
  }
}

// ---------------- fully-parallel tail: grid (12 tiles, 32 m) ----------------------
__global__ __launch_bounds__(256) void tail_all(
    const float* __restrict__ y1g, const float* __restrict__ z1g,
    const float* __restrict__ w_c2, const float* __restrict__ b_c2,
    const float* __restrict__ w_co, const float* __restrict__ b_co,
    const float* __restrict__ w_sm, const float* __restrict__ b_sm,
    const float* __restrict__ w_r2, const float* __restrict__ b_r2,
    const float* __restrict__ w_r3, const float* __restrict__ b_r3,
    const float* __restrict__ w_r4, const float* __restrict__ b_r4,
    const float* __restrict__ w_ro, const float* __restrict__ b_ro,
    const float* __restrict__ w_sg, const float* __restrict__ b_sg,
    float* __restrict__ class_out, float* __restrict__ reg_out) {
  int tile = blockIdx.x, m = blockIdx.y, t = threadIdx.x;
  if (tile < 8) {
    __shared__ float ly1[512], ly2[256], ly3[29 * 13];
    ly1[t] = y1g[m * 512 + t];
    ly1[t + 256] = y1g[m * 512 + 256 + t];
    __syncthreads();
    {
      float s = b_c2[t];
      for (int k = 0; k < 512; ++k) s = fmaf(ly1[k], w_c2[k * 256 + t], s);
      ly2[t] = s > 0.f ? s : ALPHA * s;
    }
    __syncthreads();
    int p0 = tile * 29;
    int np = 225 - p0; if (np > 29) np = 29;
    int ncols = np * 13;
    for (int n = t; n < ncols; n += 256) {
      int col = p0 * 13 + n;
      float s = b_co[col];
      for (int k = 0; k < 256; ++k) s = fmaf(ly2[k], w_co[k * 2925 + col], s);
      ly3[n] = s > 0.f ? s : ALPHA * s;
    }
    __syncthreads();
    if (t < np) {
      float v[13], l[13], mx = -1e30f;
#pragma unroll
      for (int i = 0; i < 13; ++i) v[i] = ly3[t * 13 + i];
#pragma unroll
      for (int j = 0; j < 13; ++j) {
        float s = b_sm[j];
#pragma unroll
        for (int i = 0; i < 13; ++i) s = fmaf(v[i], w_sm[i * 13 + j], s);
        l[j] = s; mx = fmaxf(mx, s);
      }
      float sum = 0.f;
#pragma unroll
      for (int j = 0; j < 13; ++j) { l[j] = expf(l[j] - mx); sum += l[j]; }
      float inv = 1.f / sum;
      float* o = class_out + ((size_t)m * 225 + p0 + t) * 13;
#pragma unroll
      for (int j = 0; j < 13; ++j) o[j] = l[j] * inv;
    }
  } else {
    __shared__ float lz1[256], lz2[128], lz3[128], lz4[64], lzo[57 * 4];
    lz1[t] = z1g[m * 256 + t];
    __syncthreads();
    if (t < 128) {
      float s = b_r2[t];
      for (int k = 0; k < 256; ++k) s = fmaf(lz1[k], w_r2[k * 128 + t], s);
      lz2[t] = s > 0.f ? s : ALPHA * s;
    }
    __syncthreads();
    if (t < 128) {
      float s = b_r3[t];
      for (int k = 0; k < 128; ++k) s = fmaf(lz2[k], w_r3[k * 128 + t], s);
      lz3[t] = s > 0.f ? s : ALPHA * s;
    }
    __syncthreads();
    if (t < 64) {
      float s = b_r4[t];
      for (int k = 0; k < 128; ++k) s = fmaf(lz3[k], w_r4[k * 64 + t], s);
      lz4[t] = s > 0.f ? s : ALPHA * s;
    }
    __syncthreads();
    int p0 = (tile - 8) * 57;
    int np = 225 - p0; if (np > 57) np = 57;
    int ncols = np * 4;
    for (int n = t; n < ncols; n += 256) {
      int col = p0 * 4 + n;
      float s = b_ro[col];
#pragma unroll
      for (int k = 0; k < 64; ++k) s = fmaf(lz4[k], w_ro[k * 900 + col], s);
      lzo[n] = s;
    }
    __syncthreads();
    if (t < np) {
      float z[4];
#pragma unroll
      for (int i = 0; i < 4; ++i) z[i] = lzo[t * 4 + i];
      float* ro = reg_out + ((size_t)m * 225 + p0 + t) * 4;
#pragma unroll
      for (int j = 0; j < 4; ++j) {
        float s = b_sg[j];
#pragma unroll
        for (int i = 0; i < 4; ++i) s = fmaf(z[i], w_sg[i * 4 + j], s);
        ro[j] = 1.f / (1.f + expf(-s));
      }
    }
  }
}

// ---------------- workspace layout (bytes) ----------------
#define OFF_P1     ((size_t)0)            // 25,229,312
#define OFF_BPACK  ((size_t)25229312)     // 36,864
#define OFF_H      ((size_t)25266176)     // 11,935,744 (bf16 h)
#define OFF_PART1  ((size_t)37201920)     // 365*16448*4 = 24,014,080
#define OFF_PART2  ((size_t)61216000)     // 365*8256*4  = 12,053,760
#define OFF_Y1     ((size_t)73269760)     // 65,536
#define OFF_Z1     ((size_t)73335296)     // 32,768

extern "C" void kernel_launch(void* const* d_in, const int* in_sizes, int n_in,
                              void* d_out, int out_size, void* d_ws, size_t ws_size,
                              hipStream_t stream) {
  const float* x     = (const float*)d_in[0];
  const float* w1    = (const float*)d_in[1];
  const float* b1    = (const float*)d_in[2];
  const float* w2    = (const float*)d_in[3];
  const float* b2    = (const float*)d_in[4];
  const float* w_c1  = (const float*)d_in[5];
  const float* b_c1  = (const float*)d_in[6];
  const float* w_c2  = (const float*)d_in[7];
  const float* b_c2  = (const float*)d_in[8];
  const float* w_co  = (const float*)d_in[9];
  const float* b_co  = (const float*)d_in[10];
  const float* w_sm  = (const float*)d_in[11];
  const float* b_sm  = (const float*)d_in[12];
  const float* w_r1  = (const float*)d_in[13];
  const float* b_r1  = (const float*)d_in[14];
  const float* w_r2  = (const float*)d_in[15];
  const float* b_r2  = (const float*)d_in[16];
  const float* w_r3  = (const float*)d_in[17];
  const float* b_r3  = (const float*)d_in[18];
  const float* w_r4  = (const float*)d_in[19];
  const float* b_r4  = (const float*)d_in[20];
  const float* w_ro  = (const float*)d_in[21];
  const float* b_ro  = (const float*)d_in[22];
  const float* w_sg  = (const float*)d_in[23];
  const float* b_sg  = (const float*)d_in[24];

  char* ws = (char*)d_ws;
  unsigned short* p1    = (unsigned short*)(ws + OFF_P1);
  unsigned short* bpack = (unsigned short*)(ws + OFF_BPACK);
  unsigned short* hbf   = (unsigned short*)(ws + OFF_H);
  float*          part1 = (float*)(ws + OFF_PART1);
  float*          part2 = (float*)(ws + OFF_PART2);
  float*          y1    = (float*)(ws + OFF_Y1);
  float*          z1    = (float*)(ws + OFF_Z1);

  float* class_out = (float*)d_out;
  float* reg_out   = (float*)d_out + 32 * 225 * 13;

  conv1_pool<<<CONV1_BLOCKS + 72, 256, 0, stream>>>(x, w1, b1, p1, w2, bpack);
  conv2_pool<<<dim3(47, 32), 256, 0, stream>>>(p1, bpack, b2, hbf);
  // INSTRUMENTATION: z=3 replicates identical (idempotent) work so this dispatch
  // exceeds the harness-fill duration and surfaces in rocprof top-5.
  gemm_mfma<512, PSTRIDE1><<<dim3(2, NGK, 3), 256, 0, stream>>>(w_c1, hbf, part1);
  gemm_mfma<256, PSTRIDE2><<<dim3(1, NGK), 256, 0, stream>>>(w_r1, hbf, part2);
  reduce_big<<<768, 256, 0, stream>>>(part1, part2, b_c1, b_r1, y1, z1);
  tail_all<<<dim3(12, 32), 256, 0, stream>>>(y1, z1,
      w_c2, b_c2, w_co, b_co, w_sm, b_sm,
      w_r2, b_r2, w_r3, b_r3, w_r4, b_r4,
      w_ro, b_ro, w_sg, b_sg, class_out, reg_out);
}

// Round 16
// 257.548 us; speedup vs baseline: 1.5286x; 1.5286x over previous
//
#include <hip/hip_runtime.h>
#include <hip/hip_bf16.h>

#define ALPHA 0.01f

typedef __attribute__((ext_vector_type(8))) __bf16 bf16x8;
typedef __attribute__((ext_vector_type(4))) float f32x4;

#define BATCH 32
#define P1H 97
#define P1W 127
#define P2W 62
#define FLAT 186496
#define GK 512
#define NGK 365               // ceil(186496/512); last chunk = 128 (4 k-steps, even)
#define PSTRIDE1 16448        // 32*512 + 64 pad (floats)
#define PSTRIDE2 8256         // 32*256 + 64 pad
#define CONV1_BLOCKS 1540
#define LPITCH 264            // 1056 B rows: 16B-aligned uint4 writes

// LDS-only barrier: orders LDS traffic but lets pending GLOBAL loads float across.
#define BAR_LDS() asm volatile("s_waitcnt lgkmcnt(0)\n\ts_barrier" ::: "memory")

static __device__ __forceinline__ unsigned short f2bf(float x) {
  union { float f; unsigned u; } c; c.f = x;
  unsigned r = c.u + 0x7fffu + ((c.u >> 16) & 1u);
  return (unsigned short)(r >> 16);
}

static __device__ __forceinline__ unsigned pack2bf(float lo, float hi) {
  union { float f; unsigned u; } a, b;
  a.f = lo; b.f = hi;
  unsigned ra = (a.u + 0x7fffu + ((a.u >> 16) & 1u)) >> 16;
  unsigned rb = (b.u + 0x7fffu + ((b.u >> 16) & 1u)) & 0xffff0000u;
  return ra | rb;
}

// ------- conv1 (3x3x1->32) + ReLU + 2x2 maxpool -> p1 bf16 ; + w2 repack ----------
__global__ __launch_bounds__(256) void conv1_pool(const float* __restrict__ x,
    const float* __restrict__ w1, const float* __restrict__ b1,
    unsigned short* __restrict__ p1,
    const float* __restrict__ w2, unsigned short* __restrict__ bpack) {
  if (blockIdx.x >= CONV1_BLOCKS) {
    int o = (blockIdx.x - CONV1_BLOCKS) * 256 + threadIdx.x;
    if (o < 9 * 4 * 512) {
      int f = o >> 9;
      int within = o & 511;
      int lane = within >> 3, j = within & 7;
      int tap = f >> 2, nf = f & 3;
      int k = ((lane >> 4) << 3) + j;
      int n = nf * 16 + (lane & 15);
      bpack[o] = f2bf(w2[(tap * 32 + k) * 64 + n]);
    }
    return;
  }
  int pid = blockIdx.x * 256 + threadIdx.x;
  if (pid >= BATCH * P1H * P1W) return;
  int b = pid / (P1H * P1W);
  int rem = pid - b * (P1H * P1W);
  int ph = rem / P1W;
  int pw = rem - ph * P1W;
  const float* xb = x + ((b * 197 + 2 * ph) * 256 + 2 * pw);
  float in[4][4];
#pragma unroll
  for (int r = 0; r < 4; ++r) {
    float2 v0 = *reinterpret_cast<const float2*>(xb + r * 256);
    float2 v1 = *reinterpret_cast<const float2*>(xb + r * 256 + 2);
    in[r][0] = v0.x; in[r][1] = v0.y; in[r][2] = v1.x; in[r][3] = v1.y;
  }
  unsigned pk[16];
#pragma unroll
  for (int c = 0; c < 32; ++c) {
    float s00 = b1[c], s01 = s00, s10 = s00, s11 = s00;
#pragma unroll
    for (int ky = 0; ky < 3; ++ky)
#pragma unroll
      for (int kx = 0; kx < 3; ++kx) {
        float w = w1[(ky * 3 + kx) * 32 + c];
        s00 = fmaf(in[ky][kx], w, s00);
        s01 = fmaf(in[ky][kx + 1], w, s01);
        s10 = fmaf(in[ky + 1][kx], w, s10);
        s11 = fmaf(in[ky + 1][kx + 1], w, s11);
      }
    float m = fmaxf(fmaxf(s00, s01), fmaxf(s10, s11));
    m = fmaxf(m, 0.0f);
    unsigned short u = f2bf(m);
    if (c & 1) pk[c >> 1] |= ((unsigned)u) << 16;
    else pk[c >> 1] = (unsigned)u;
  }
  uint4* dst = reinterpret_cast<uint4*>(p1 + (size_t)pid * 32);
#pragma unroll
  for (int g = 0; g < 4; ++g)
    dst[g] = make_uint4(pk[g * 4], pk[g * 4 + 1], pk[g * 4 + 2], pk[g * 4 + 3]);
}

// ---------------- conv2 (3x3x32->64) MFMA + bias + ReLU + 2x2 maxpool -> h bf16 ----
__global__ __launch_bounds__(256) void conv2_pool(const unsigned short* __restrict__ p1,
    const unsigned short* __restrict__ bpack, const float* __restrict__ b2,
    unsigned short* __restrict__ hbf) {
  __shared__ alignas(16) unsigned char lds_buf[65536];
  int prow = blockIdx.x, b = blockIdx.y;
  int tid = threadIdx.x;
  int lane = tid & 63, wid = tid >> 6;
  {
    const uint4* src = reinterpret_cast<const uint4*>(bpack);
    uint4* dst = reinterpret_cast<uint4*>(lds_buf);
    for (int i = tid; i < 2304; i += 256) dst[i] = src[i];
  }
  __syncthreads();
  int row = lane & 15, kg = lane >> 4;
  int rowbase[4];
  int coff[4][3];
#pragma unroll
  for (int mf = 0; mf < 4; ++mf) {
    int m = wid * 64 + mf * 16 + row;
    int cro = m >> 7, cc = m & 127;
    rowbase[mf] = ((b * 97 + 2 * prow + cro) * 127) * 32 + kg * 8;
#pragma unroll
    for (int kx = 0; kx < 3; ++kx) {
      int ic = cc + kx; if (ic > 126) ic = 126;
      coff[mf][kx] = ic * 32;
    }
  }
  f32x4 acc[4][4];
#pragma unroll
  for (int i = 0; i < 4; ++i)
#pragma unroll
    for (int j = 0; j < 4; ++j) acc[i][j] = (f32x4){0.f, 0.f, 0.f, 0.f};

  const bf16x8* bl = reinterpret_cast<const bf16x8*>(lds_buf);
#pragma unroll
  for (int ky = 0; ky < 3; ++ky) {
#pragma unroll
    for (int kx = 0; kx < 3; ++kx) {
      int tap = ky * 3 + kx;
      bf16x8 a[4];
#pragma unroll
      for (int mf = 0; mf < 4; ++mf) {
        int addr = rowbase[mf] + ky * (127 * 32) + coff[mf][kx];
        a[mf] = *reinterpret_cast<const bf16x8*>(p1 + addr);
      }
      bf16x8 bf[4];
#pragma unroll
      for (int nf = 0; nf < 4; ++nf) bf[nf] = bl[(tap * 4 + nf) * 64 + lane];
#pragma unroll
      for (int nf = 0; nf < 4; ++nf)
#pragma unroll
        for (int mf = 0; mf < 4; ++mf)
          acc[mf][nf] = __builtin_amdgcn_mfma_f32_16x16x32_bf16(a[mf], bf[nf], acc[mf][nf], 0, 0, 0);
    }
  }
  __syncthreads();
  float* stage = reinterpret_cast<float*>(lds_buf);
#pragma unroll
  for (int mf = 0; mf < 4; ++mf)
#pragma unroll
    for (int nf = 0; nf < 4; ++nf) {
      int ch = nf * 16 + (lane & 15);
      float bias = b2[ch];
#pragma unroll
      for (int j = 0; j < 4; ++j) {
        int m = wid * 64 + mf * 16 + (lane >> 4) * 4 + j;
        float v = acc[mf][nf][j] + bias;
        stage[m * 64 + ch] = fmaxf(v, 0.f);
      }
    }
  __syncthreads();
  unsigned short* hb = hbf + (size_t)b * FLAT + prow * (P2W * 64);
  for (int o = tid; o < P2W * 64; o += 256) {
    int pw = o >> 6, ch = o & 63;
    int c0 = 2 * pw;
    float v = fmaxf(fmaxf(stage[c0 * 64 + ch], stage[(c0 + 1) * 64 + ch]),
                    fmaxf(stage[(128 + c0) * 64 + ch], stage[(129 + c0) * 64 + ch]));
    hb[o] = f2bf(v);
  }
}

// ------- MFMA big GEMM: 1KB row bursts + LDS-only barriers + DEPTH-2 prefetch -----
// Grid (N/256, NGK). Block 256 thr = 4 waves, owns 256-col x GK-k panel.
// Two register sets sA/sB; loop unrolled x2 (static indices). PACK of step kt
// waits (counted vmcnt) for loads issued at kt-2 (~1800 cy earlier) while the
// 8 loads of kt-1 stay outstanding — full HBM-latency cover, no vmcnt drains.
template <int N, int CSTRIDE>
__global__ __launch_bounds__(256) void gemm_mfma(const float* __restrict__ W,
    const unsigned short* __restrict__ hbf, float* __restrict__ part) {
  __shared__ alignas(16) unsigned lds[16 * LPITCH];   // 16.5 KB
  int kc = blockIdx.y;
  int n0 = blockIdx.x * 256;
  int t = threadIdx.x, lane = t & 63, w = t >> 6;
  int k0 = kc * GK;
  int klen = FLAT - k0; if (klen > GK) klen = GK;
  int nsteps = klen >> 5;              // 16 or 4 — always even, >= 4
  int cl = lane & 15, kg = lane >> 4;
  int mh = w & 1, nh = w >> 1;
  int kgl = kg & 1;
  size_t kstep = (size_t)32 * N;

  const float* wsrc = W + (size_t)(k0 + w * 8) * N + n0 + lane * 4;
  unsigned* lwb = lds + (w * 4) * LPITCH + ((lane * 4) ^ ((w & 1) << 4));
  const unsigned short* ha = hbf + (size_t)(mh * 16 + cl) * FLAT + k0 + kg * 8;

  f32x4 acc[8];
#pragma unroll
  for (int f = 0; f < 8; ++f) acc[f] = (f32x4){0.f, 0.f, 0.f, 0.f};

  float4 sA[8], sB[8];
  bf16x8 a_cur, a_nxt;

#define LOAD8(dst, ptr)                                                        \
  _Pragma("unroll") for (int i_ = 0; i_ < 8; ++i_)                             \
    dst[i_] = *reinterpret_cast<const float4*>((ptr) + (size_t)i_ * N);

#define PACK8(src)                                                             \
  _Pragma("unroll") for (int ip_ = 0; ip_ < 4; ++ip_) {                        \
    float4 lo_ = src[2 * ip_], hi_ = src[2 * ip_ + 1];                         \
    *reinterpret_cast<uint4*>(lwb + ip_ * LPITCH) =                            \
        make_uint4(pack2bf(lo_.x, hi_.x), pack2bf(lo_.y, hi_.y),               \
                   pack2bf(lo_.z, hi_.z), pack2bf(lo_.w, hi_.w));              \
  }

#define MFMA8(areg)                                                            \
  _Pragma("unroll") for (int f_ = 0; f_ < 8; ++f_) {                           \
    int col_ = nh * 128 + ((f_ ^ kgl) * 16) + cl;                              \
    union { unsigned u[4]; bf16x8 v; } bb_;                                    \
    _Pragma("unroll") for (int p_ = 0; p_ < 4; ++p_)                           \
      bb_.u[p_] = lds[(kg * 4 + p_) * LPITCH + col_];                          \
    acc[f_] = __builtin_amdgcn_mfma_f32_16x16x32_bf16(areg, bb_.v, acc[f_], 0, 0, 0); \
  }

  // prologue: issue W(0), W(1); A(0)
  a_cur = *reinterpret_cast<const bf16x8*>(ha);
  LOAD8(sA, wsrc);
  LOAD8(sB, wsrc + kstep);

  for (int kt = 0; kt < nsteps; kt += 2) {
    // even sub-step: consume sA = W(kt); refill sA with W(kt+2)
    BAR_LDS();
    PACK8(sA);                               // counted vmcnt: waits sA only
    if (kt + 2 < nsteps) { LOAD8(sA, wsrc + (size_t)(kt + 2) * kstep); }
    BAR_LDS();
    if (kt + 1 < nsteps)
      a_nxt = *reinterpret_cast<const bf16x8*>(ha + (kt + 1) * 32);
    MFMA8(a_cur);
    a_cur = a_nxt;
    // odd sub-step: consume sB = W(kt+1); refill sB with W(kt+3)
    BAR_LDS();
    PACK8(sB);
    if (kt + 3 < nsteps) { LOAD8(sB, wsrc + (size_t)(kt + 3) * kstep); }
    BAR_LDS();
    if (kt + 2 < nsteps)
      a_nxt = *reinterpret_cast<const bf16x8*>(ha + (kt + 2) * 32);
    MFMA8(a_cur);
    a_cur = a_nxt;
  }
#undef LOAD8
#undef PACK8
#undef MFMA8

  float* out = part + (size_t)kc * CSTRIDE + n0;
#pragma unroll
  for (int f = 0; f < 8; ++f)
#pragma unroll
    for (int j = 0; j < 4; ++j) {
      int m = mh * 16 + kg * 4 + j;
      int col = nh * 128 + f * 16 + cl;   // logical column (swizzle resolved)
      out[m * N + col] = acc[f][j];
    }
}

// ---------------- reduce split-K partials: 768 blocks, 8 threads/output ----------
__global__ __launch_bounds__(256) void reduce_big(const float* __restrict__ part1,
    const float* __restrict__ part2, const float* __restrict__ b_c1,
    const float* __restrict__ b_r1, float* __restrict__ y1, float* __restrict__ z1) {
  __shared__ float red[8][32];
  int b = blockIdx.x, t = threadIdx.x;
  int oo = t & 31, j = t >> 5;
  float s = 0.f;
  if (b < 512) {
    const float* p = part1 + b * 32 + oo;
    for (int c = j; c < NGK; c += 8) s += p[(size_t)c * PSTRIDE1];
    red[j][oo] = s;
    __syncthreads();
    if (t < 32) {
      float r = 0.f;
#pragma unroll
      for (int jj = 0; jj < 8; ++jj) r += red[jj][t];
      int o = b * 32 + t;
      r += b_c1[o & 511];
      y1[o] = r > 0.f ? r : ALPHA * r;
    }
  } else {
    const float* p = part2 + (b - 512) * 32 + oo;
    for (int c = j; c < NGK; c += 8) s += p[(size_t)c * PSTRIDE2];
    red[j][oo] = s;
    __syncthreads();
    if (t < 32) {
      float r = 0.f;
#pragma unroll
      for (int jj = 0; jj < 8; ++jj) r += red[jj][t];
      int u = (b - 512) * 32 + t;
      r += b_r1[u & 255];
      z1[u] = r > 0.f ? r : ALPHA * r;
    }
  }
}

// ---------------- fully-parallel tail: grid (12 tiles, 32 m) ----------------------
__global__ __launch_bounds__(256) void tail_all(
    const float* __restrict__ y1g, const float* __restrict__ z1g,
    const float* __restrict__ w_c2, const float* __restrict__ b_c2,
    const float* __restrict__ w_co, const float* __restrict__ b_co,
    const float* __restrict__ w_sm, const float* __restrict__ b_sm,
    const float* __restrict__ w_r2, const float* __restrict__ b_r2,
    const float* __restrict__ w_r3, const float* __restrict__ b_r3,
    const float* __restrict__ w_r4, const float* __restrict__ b_r4,
    const float* __restrict__ w_ro, const float* __restrict__ b_ro,
    const float* __restrict__ w_sg, const float* __restrict__ b_sg,
    float* __restrict__ class_out, float* __restrict__ reg_out) {
  int tile = blockIdx.x, m = blockIdx.y, t = threadIdx.x;
  if (tile < 8) {
    __shared__ float ly1[512], ly2[256], ly3[29 * 13];
    ly1[t] = y1g[m * 512 + t];
    ly1[t + 256] = y1g[m * 512 + 256 + t];
    __syncthreads();
    {
      float s = b_c2[t];
      for (int k = 0; k < 512; ++k) s = fmaf(ly1[k], w_c2[k * 256 + t], s);
      ly2[t] = s > 0.f ? s : ALPHA * s;
    }
    __syncthreads();
    int p0 = tile * 29;
    int np = 225 - p0; if (np > 29) np = 29;
    int ncols = np * 13;
    for (int n = t; n < ncols; n += 256) {
      int col = p0 * 13 + n;
      float s = b_co[col];
      for (int k = 0; k < 256; ++k) s = fmaf(ly2[k], w_co[k * 2925 + col], s);
      ly3[n] = s > 0.f ? s : ALPHA * s;
    }
    __syncthreads();
    if (t < np) {
      float v[13], l[13], mx = -1e30f;
#pragma unroll
      for (int i = 0; i < 13; ++i) v[i] = ly3[t * 13 + i];
#pragma unroll
      for (int j = 0; j < 13; ++j) {
        float s = b_sm[j];
#pragma unroll
        for (int i = 0; i < 13; ++i) s = fmaf(v[i], w_sm[i * 13 + j], s);
        l[j] = s; mx = fmaxf(mx, s);
      }
      float sum = 0.f;
#pragma unroll
      for (int j = 0; j < 13; ++j) { l[j] = expf(l[j] - mx); sum += l[j]; }
      float inv = 1.f / sum;
      float* o = class_out + ((size_t)m * 225 + p0 + t) * 13;
#pragma unroll
      for (int j = 0; j < 13; ++j) o[j] = l[j] * inv;
    }
  } else {
    __shared__ float lz1[256], lz2[128], lz3[128], lz4[64], lzo[57 * 4];
    lz1[t] = z1g[m * 256 + t];
    __syncthreads();
    if (t < 128) {
      float s = b_r2[t];
      for (int k = 0; k < 256; ++k) s = fmaf(lz1[k], w_r2[k * 128 + t], s);
      lz2[t] = s > 0.f ? s : ALPHA * s;
    }
    __syncthreads();
    if (t < 128) {
      float s = b_r3[t];
      for (int k = 0; k < 128; ++k) s = fmaf(lz2[k], w_r3[k * 128 + t], s);
      lz3[t] = s > 0.f ? s : ALPHA * s;
    }
    __syncthreads();
    if (t < 64) {
      float s = b_r4[t];
      for (int k = 0; k < 128; ++k) s = fmaf(lz3[k], w_r4[k * 64 + t], s);
      lz4[t] = s > 0.f ? s : ALPHA * s;
    }
    __syncthreads();
    int p0 = (tile - 8) * 57;
    int np = 225 - p0; if (np > 57) np = 57;
    int ncols = np * 4;
    for (int n = t; n < ncols; n += 256) {
      int col = p0 * 4 + n;
      float s = b_ro[col];
#pragma unroll
      for (int k = 0; k < 64; ++k) s = fmaf(lz4[k], w_ro[k * 900 + col], s);
      lzo[n] = s;
    }
    __syncthreads();
    if (t < np) {
      float z[4];
#pragma unroll
      for (int i = 0; i < 4; ++i) z[i] = lzo[t * 4 + i];
      float* ro = reg_out + ((size_t)m * 225 + p0 + t) * 4;
#pragma unroll
      for (int j = 0; j < 4; ++j) {
        float s = b_sg[j];
#pragma unroll
        for (int i = 0; i < 4; ++i) s = fmaf(z[i], w_sg[i * 4 + j], s);
        ro[j] = 1.f / (1.f + expf(-s));
      }
    }
  }
}

// ---------------- workspace layout (bytes) ----------------
#define OFF_P1     ((size_t)0)            // 25,229,312
#define OFF_BPACK  ((size_t)25229312)     // 36,864
#define OFF_H      ((size_t)25266176)     // 11,935,744 (bf16 h)
#define OFF_PART1  ((size_t)37201920)     // 365*16448*4 = 24,014,080
#define OFF_PART2  ((size_t)61216000)     // 365*8256*4  = 12,053,760
#define OFF_Y1     ((size_t)73269760)     // 65,536
#define OFF_Z1     ((size_t)73335296)     // 32,768

extern "C" void kernel_launch(void* const* d_in, const int* in_sizes, int n_in,
                              void* d_out, int out_size, void* d_ws, size_t ws_size,
                              hipStream_t stream) {
  const float* x     = (const float*)d_in[0];
  const float* w1    = (const float*)d_in[1];
  const float* b1    = (const float*)d_in[2];
  const float* w2    = (const float*)d_in[3];
  const float* b2    = (const float*)d_in[4];
  const float* w_c1  = (const float*)d_in[5];
  const float* b_c1  = (const float*)d_in[6];
  const float* w_c2  = (const float*)d_in[7];
  const float* b_c2  = (const float*)d_in[8];
  const float* w_co  = (const float*)d_in[9];
  const float* b_co  = (const float*)d_in[10];
  const float* w_sm  = (const float*)d_in[11];
  const float* b_sm  = (const float*)d_in[12];
  const float* w_r1  = (const float*)d_in[13];
  const float* b_r1  = (const float*)d_in[14];
  const float* w_r2  = (const float*)d_in[15];
  const float* b_r2  = (const float*)d_in[16];
  const float* w_r3  = (const float*)d_in[17];
  const float* b_r3  = (const float*)d_in[18];
  const float* w_r4  = (const float*)d_in[19];
  const float* b_r4  = (const float*)d_in[20];
  const float* w_ro  = (const float*)d_in[21];
  const float* b_ro  = (const float*)d_in[22];
  const float* w_sg  = (const float*)d_in[23];
  const float* b_sg  = (const float*)d_in[24];

  char* ws = (char*)d_ws;
  unsigned short* p1    = (unsigned short*)(ws + OFF_P1);
  unsigned short* bpack = (unsigned short*)(ws + OFF_BPACK);
  unsigned short* hbf   = (unsigned short*)(ws + OFF_H);
  float*          part1 = (float*)(ws + OFF_PART1);
  float*          part2 = (float*)(ws + OFF_PART2);
  float*          y1    = (float*)(ws + OFF_Y1);
  float*          z1    = (float*)(ws + OFF_Z1);

  float* class_out = (float*)d_out;
  float* reg_out   = (float*)d_out + 32 * 225 * 13;

  conv1_pool<<<CONV1_BLOCKS + 72, 256, 0, stream>>>(x, w1, b1, p1, w2, bpack);
  conv2_pool<<<dim3(47, 32), 256, 0, stream>>>(p1, bpack, b2, hbf);
  gemm_mfma<512, PSTRIDE1><<<dim3(2, NGK), 256, 0, stream>>>(w_c1, hbf, part1);
  gemm_mfma<256, PSTRIDE2><<<dim3(1, NGK), 256, 0, stream>>>(w_r1, hbf, part2);
  reduce_big<<<768, 256, 0, stream>>>(part1, part2, b_c1, b_r1, y1, z1);
  tail_all<<<dim3(12, 32), 256, 0, stream>>>(y1, z1,
      w_c2, b_c2, w_co, b_co, w_sm, b_sm,
      w_r2, b_r2, w_r3, b_r3, w_r4, b_r4,
      w_ro, b_ro, w_sg, b_sg, class_out, reg_out);
}

// Round 17
// 243.517 us; speedup vs baseline: 1.6167x; 1.0576x over previous
//
#include <hip/hip_runtime.h>
#include <hip/hip_bf16.h>

#define ALPHA 0.01f

typedef __attribute__((ext_vector_type(8))) __bf16 bf16x8;
typedef __attribute__((ext_vector_type(4))) float f32x4;

#define BATCH 32
#define P1H 97
#define P1W 127
#define P2W 62
#define FLAT 186496
#define GK 512
#define NGK 365               // ceil(186496/512); last chunk = 128 (4 k-steps)
#define PSTRIDE1 16448        // 32*512 + 64 pad (floats)
#define PSTRIDE2 8256         // 32*256 + 64 pad
#define CONV1_BLOCKS 1540
#define LPITCH 264            // 1056 B rows: 16B-aligned uint4 writes

// LDS-only barrier: orders LDS traffic but lets pending GLOBAL loads float across.
#define BAR_LDS() asm volatile("s_waitcnt lgkmcnt(0)\n\ts_barrier" ::: "memory")

static __device__ __forceinline__ unsigned short f2bf(float x) {
  union { float f; unsigned u; } c; c.f = x;
  unsigned r = c.u + 0x7fffu + ((c.u >> 16) & 1u);
  return (unsigned short)(r >> 16);
}

static __device__ __forceinline__ unsigned pack2bf(float lo, float hi) {
  union { float f; unsigned u; } a, b;
  a.f = lo; b.f = hi;
  unsigned ra = (a.u + 0x7fffu + ((a.u >> 16) & 1u)) >> 16;
  unsigned rb = (b.u + 0x7fffu + ((b.u >> 16) & 1u)) & 0xffff0000u;
  return ra | rb;
}

// ------- conv1 (3x3x1->32) + ReLU + 2x2 maxpool -> p1 bf16 ; + w2 repack ----------
__global__ __launch_bounds__(256) void conv1_pool(const float* __restrict__ x,
    const float* __restrict__ w1, const float* __restrict__ b1,
    unsigned short* __restrict__ p1,
    const float* __restrict__ w2, unsigned short* __restrict__ bpack) {
  if (blockIdx.x >= CONV1_BLOCKS) {
    int o = (blockIdx.x - CONV1_BLOCKS) * 256 + threadIdx.x;
    if (o < 9 * 4 * 512) {
      int f = o >> 9;
      int within = o & 511;
      int lane = within >> 3, j = within & 7;
      int tap = f >> 2, nf = f & 3;
      int k = ((lane >> 4) << 3) + j;
      int n = nf * 16 + (lane & 15);
      bpack[o] = f2bf(w2[(tap * 32 + k) * 64 + n]);
    }
    return;
  }
  int pid = blockIdx.x * 256 + threadIdx.x;
  if (pid >= BATCH * P1H * P1W) return;
  int b = pid / (P1H * P1W);
  int rem = pid - b * (P1H * P1W);
  int ph = rem / P1W;
  int pw = rem - ph * P1W;
  const float* xb = x + ((b * 197 + 2 * ph) * 256 + 2 * pw);
  float in[4][4];
#pragma unroll
  for (int r = 0; r < 4; ++r) {
    float2 v0 = *reinterpret_cast<const float2*>(xb + r * 256);
    float2 v1 = *reinterpret_cast<const float2*>(xb + r * 256 + 2);
    in[r][0] = v0.x; in[r][1] = v0.y; in[r][2] = v1.x; in[r][3] = v1.y;
  }
  unsigned pk[16];
#pragma unroll
  for (int c = 0; c < 32; ++c) {
    float s00 = b1[c], s01 = s00, s10 = s00, s11 = s00;
#pragma unroll
    for (int ky = 0; ky < 3; ++ky)
#pragma unroll
      for (int kx = 0; kx < 3; ++kx) {
        float w = w1[(ky * 3 + kx) * 32 + c];
        s00 = fmaf(in[ky][kx], w, s00);
        s01 = fmaf(in[ky][kx + 1], w, s01);
        s10 = fmaf(in[ky + 1][kx], w, s10);
        s11 = fmaf(in[ky + 1][kx + 1], w, s11);
      }
    float m = fmaxf(fmaxf(s00, s01), fmaxf(s10, s11));
    m = fmaxf(m, 0.0f);
    unsigned short u = f2bf(m);
    if (c & 1) pk[c >> 1] |= ((unsigned)u) << 16;
    else pk[c >> 1] = (unsigned)u;
  }
  uint4* dst = reinterpret_cast<uint4*>(p1 + (size_t)pid * 32);
#pragma unroll
  for (int g = 0; g < 4; ++g)
    dst[g] = make_uint4(pk[g * 4], pk[g * 4 + 1], pk[g * 4 + 2], pk[g * 4 + 3]);
}

// ------- conv2 (3x3x32->64) MFMA + bias + ReLU + 2x2 maxpool -> h bf16 ------------
// LDS cut 64KB -> 36.9KB: pool stage stored as bf16 (32KB) OVERLAPPED into the
// bpack region (dead after last MFMA + barrier). 4 blocks/CU instead of 2.
// Numerics identical: rounding monotone => max(f2bf(x)) == f2bf(max(x)); post-ReLU
// bf16 patterns are non-negative so integer max == value max.
__global__ __launch_bounds__(256) void conv2_pool(const unsigned short* __restrict__ p1,
    const unsigned short* __restrict__ bpack, const float* __restrict__ b2,
    unsigned short* __restrict__ hbf) {
  __shared__ alignas(16) unsigned char lds_buf[36864];
  int prow = blockIdx.x, b = blockIdx.y;
  int tid = threadIdx.x;
  int lane = tid & 63, wid = tid >> 6;
  {
    const uint4* src = reinterpret_cast<const uint4*>(bpack);
    uint4* dst = reinterpret_cast<uint4*>(lds_buf);
    for (int i = tid; i < 2304; i += 256) dst[i] = src[i];
  }
  __syncthreads();
  int row = lane & 15, kg = lane >> 4;
  int rowbase[4];
  int coff[4][3];
#pragma unroll
  for (int mf = 0; mf < 4; ++mf) {
    int m = wid * 64 + mf * 16 + row;
    int cro = m >> 7, cc = m & 127;
    rowbase[mf] = ((b * 97 + 2 * prow + cro) * 127) * 32 + kg * 8;
#pragma unroll
    for (int kx = 0; kx < 3; ++kx) {
      int ic = cc + kx; if (ic > 126) ic = 126;
      coff[mf][kx] = ic * 32;
    }
  }
  f32x4 acc[4][4];
#pragma unroll
  for (int i = 0; i < 4; ++i)
#pragma unroll
    for (int j = 0; j < 4; ++j) acc[i][j] = (f32x4){0.f, 0.f, 0.f, 0.f};

  const bf16x8* bl = reinterpret_cast<const bf16x8*>(lds_buf);
#pragma unroll
  for (int ky = 0; ky < 3; ++ky) {
#pragma unroll
    for (int kx = 0; kx < 3; ++kx) {
      int tap = ky * 3 + kx;
      bf16x8 a[4];
#pragma unroll
      for (int mf = 0; mf < 4; ++mf) {
        int addr = rowbase[mf] + ky * (127 * 32) + coff[mf][kx];
        a[mf] = *reinterpret_cast<const bf16x8*>(p1 + addr);
      }
      bf16x8 bf[4];
#pragma unroll
      for (int nf = 0; nf < 4; ++nf) bf[nf] = bl[(tap * 4 + nf) * 64 + lane];
#pragma unroll
      for (int nf = 0; nf < 4; ++nf)
#pragma unroll
        for (int mf = 0; mf < 4; ++mf)
          acc[mf][nf] = __builtin_amdgcn_mfma_f32_16x16x32_bf16(a[mf], bf[nf], acc[mf][nf], 0, 0, 0);
    }
  }
  __syncthreads();                       // bpack dead; reuse LDS as bf16 stage
  unsigned short* stage = reinterpret_cast<unsigned short*>(lds_buf);
#pragma unroll
  for (int mf = 0; mf < 4; ++mf)
#pragma unroll
    for (int nf = 0; nf < 4; ++nf) {
      int ch = nf * 16 + (lane & 15);
      float bias = b2[ch];
#pragma unroll
      for (int j = 0; j < 4; ++j) {
        int m = wid * 64 + mf * 16 + (lane >> 4) * 4 + j;
        float v = acc[mf][nf][j] + bias;
        stage[m * 64 + ch] = f2bf(fmaxf(v, 0.f));
      }
    }
  __syncthreads();
  unsigned short* hb = hbf + (size_t)b * FLAT + prow * (P2W * 64);
  for (int o = tid; o < P2W * 64; o += 256) {
    int pw = o >> 6, ch = o & 63;
    int c0 = 2 * pw;
    unsigned short v0 = stage[c0 * 64 + ch], v1 = stage[(c0 + 1) * 64 + ch];
    unsigned short v2 = stage[(128 + c0) * 64 + ch], v3 = stage[(129 + c0) * 64 + ch];
    unsigned short m01 = v0 > v1 ? v0 : v1;
    unsigned short m23 = v2 > v3 ? v2 : v3;
    hb[o] = m01 > m23 ? m01 : m23;
  }
}

// ------- MFMA big GEMM, MERGED: grid (3, NGK) -----------------------------------
// Panels 0,1 = w_c1 (n0=0/256) -> part1; panel 2 = w_r1 -> part2. 1095 blocks so
// the N=256 work rides co-resident with N=512 (was 365 blocks = 1.4/CU alone).
// r14 inner structure: 1KB row bursts, depth-1 reg prefetch, BAR_LDS barriers.
__global__ __launch_bounds__(256) void gemm_mfma(
    const float* __restrict__ w_c1, const float* __restrict__ w_r1,
    const unsigned short* __restrict__ hbf,
    float* __restrict__ part1, float* __restrict__ part2) {
  __shared__ alignas(16) unsigned lds[16 * LPITCH];   // 16.5 KB
  int py = blockIdx.x, kc = blockIdx.y;
  const float* W; int N, n0, cstride; float* pbase;
  if (py < 2) { W = w_c1; N = 512; n0 = py * 256; pbase = part1; cstride = PSTRIDE1; }
  else        { W = w_r1; N = 256; n0 = 0;        pbase = part2; cstride = PSTRIDE2; }
  int t = threadIdx.x, lane = t & 63, w = t >> 6;
  int k0 = kc * GK;
  int klen = FLAT - k0; if (klen > GK) klen = GK;
  int nsteps = klen >> 5;
  int cl = lane & 15, kg = lane >> 4;
  int mh = w & 1, nh = w >> 1;
  int kgl = kg & 1;

  const float* wsrc = W + (size_t)(k0 + w * 8) * N + n0 + lane * 4;
  unsigned* lwb = lds + (w * 4) * LPITCH + ((lane * 4) ^ ((w & 1) << 4));
  const unsigned short* ha = hbf + (size_t)(mh * 16 + cl) * FLAT + k0 + kg * 8;

  f32x4 acc[8];
#pragma unroll
  for (int f = 0; f < 8; ++f) acc[f] = (f32x4){0.f, 0.f, 0.f, 0.f};

  float4 st[8];
  bf16x8 a_cur, a_nxt;
  a_cur = *reinterpret_cast<const bf16x8*>(ha);
#pragma unroll
  for (int i = 0; i < 8; ++i)
    st[i] = *reinterpret_cast<const float4*>(wsrc + (size_t)i * N);

  for (int kt = 0; kt < nsteps; ++kt) {
    BAR_LDS();                       // A: prior readers done (no vmcnt drain)
#pragma unroll
    for (int ip = 0; ip < 4; ++ip) { // pack k-pairs of st(kt), write LDS
      float4 lo = st[2 * ip], hi = st[2 * ip + 1];
      *reinterpret_cast<uint4*>(lwb + ip * LPITCH) =
          make_uint4(pack2bf(lo.x, hi.x), pack2bf(lo.y, hi.y),
                     pack2bf(lo.z, hi.z), pack2bf(lo.w, hi.w));
    }
    if (kt + 1 < nsteps) {           // issue next step's W bursts immediately
      const float* ws = wsrc + (size_t)(kt + 1) * 32 * N;
#pragma unroll
      for (int i = 0; i < 8; ++i)
        st[i] = *reinterpret_cast<const float4*>(ws + (size_t)i * N);
    }
    BAR_LDS();                       // B: tile visible (no vmcnt drain)
    if (kt + 1 < nsteps)
      a_nxt = *reinterpret_cast<const bf16x8*>(ha + (kt + 1) * 32);
#pragma unroll
    for (int f = 0; f < 8; ++f) {
      int col = nh * 128 + ((f ^ kgl) * 16) + cl;   // swizzled storage addr
      union { unsigned u[4]; bf16x8 v; } bb;
#pragma unroll
      for (int p = 0; p < 4; ++p)
        bb.u[p] = lds[(kg * 4 + p) * LPITCH + col];
      acc[f] = __builtin_amdgcn_mfma_f32_16x16x32_bf16(a_cur, bb.v, acc[f], 0, 0, 0);
    }
    a_cur = a_nxt;
  }

  float* out = pbase + (size_t)kc * cstride + n0;
#pragma unroll
  for (int f = 0; f < 8; ++f)
#pragma unroll
    for (int j = 0; j < 4; ++j) {
      int m = mh * 16 + kg * 4 + j;
      int col = nh * 128 + f * 16 + cl;   // logical column (swizzle resolved)
      out[m * N + col] = acc[f][j];
    }
}

// ---------------- reduce split-K partials: 768 blocks, 8 threads/output ----------
__global__ __launch_bounds__(256) void reduce_big(const float* __restrict__ part1,
    const float* __restrict__ part2, const float* __restrict__ b_c1,
    const float* __restrict__ b_r1, float* __restrict__ y1, float* __restrict__ z1) {
  __shared__ float red[8][32];
  int b = blockIdx.x, t = threadIdx.x;
  int oo = t & 31, j = t >> 5;
  float s = 0.f;
  if (b < 512) {
    const float* p = part1 + b * 32 + oo;
    for (int c = j; c < NGK; c += 8) s += p[(size_t)c * PSTRIDE1];
    red[j][oo] = s;
    __syncthreads();
    if (t < 32) {
      float r = 0.f;
#pragma unroll
      for (int jj = 0; jj < 8; ++jj) r += red[jj][t];
      int o = b * 32 + t;
      r += b_c1[o & 511];
      y1[o] = r > 0.f ? r : ALPHA * r;
    }
  } else {
    const float* p = part2 + (b - 512) * 32 + oo;
    for (int c = j; c < NGK; c += 8) s += p[(size_t)c * PSTRIDE2];
    red[j][oo] = s;
    __syncthreads();
    if (t < 32) {
      float r = 0.f;
#pragma unroll
      for (int jj = 0; jj < 8; ++jj) r += red[jj][t];
      int u = (b - 512) * 32 + t;
      r += b_r1[u & 255];
      z1[u] = r > 0.f ? r : ALPHA * r;
    }
  }
}

// ---------------- fully-parallel tail: grid (12 tiles, 32 m) ----------------------
__global__ __launch_bounds__(256) void tail_all(
    const float* __restrict__ y1g, const float* __restrict__ z1g,
    const float* __restrict__ w_c2, const float* __restrict__ b_c2,
    const float* __restrict__ w_co, const float* __restrict__ b_co,
    const float* __restrict__ w_sm, const float* __restrict__ b_sm,
    const float* __restrict__ w_r2, const float* __restrict__ b_r2,
    const float* __restrict__ w_r3, const float* __restrict__ b_r3,
    const float* __restrict__ w_r4, const float* __restrict__ b_r4,
    const float* __restrict__ w_ro, const float* __restrict__ b_ro,
    const float* __restrict__ w_sg, const float* __restrict__ b_sg,
    float* __restrict__ class_out, float* __restrict__ reg_out) {
  int tile = blockIdx.x, m = blockIdx.y, t = threadIdx.x;
  if (tile < 8) {
    __shared__ float ly1[512], ly2[256], ly3[29 * 13];
    ly1[t] = y1g[m * 512 + t];
    ly1[t + 256] = y1g[m * 512 + 256 + t];
    __syncthreads();
    {
      float s = b_c2[t];
      for (int k = 0; k < 512; ++k) s = fmaf(ly1[k], w_c2[k * 256 + t], s);
      ly2[t] = s > 0.f ? s : ALPHA * s;
    }
    __syncthreads();
    int p0 = tile * 29;
    int np = 225 - p0; if (np > 29) np = 29;
    int ncols = np * 13;
    for (int n = t; n < ncols; n += 256) {
      int col = p0 * 13 + n;
      float s = b_co[col];
      for (int k = 0; k < 256; ++k) s = fmaf(ly2[k], w_co[k * 2925 + col], s);
      ly3[n] = s > 0.f ? s : ALPHA * s;
    }
    __syncthreads();
    if (t < np) {
      float v[13], l[13], mx = -1e30f;
#pragma unroll
      for (int i = 0; i < 13; ++i) v[i] = ly3[t * 13 + i];
#pragma unroll
      for (int j = 0; j < 13; ++j) {
        float s = b_sm[j];
#pragma unroll
        for (int i = 0; i < 13; ++i) s = fmaf(v[i], w_sm[i * 13 + j], s);
        l[j] = s; mx = fmaxf(mx, s);
      }
      float sum = 0.f;
#pragma unroll
      for (int j = 0; j < 13; ++j) { l[j] = expf(l[j] - mx); sum += l[j]; }
      float inv = 1.f / sum;
      float* o = class_out + ((size_t)m * 225 + p0 + t) * 13;
#pragma unroll
      for (int j = 0; j < 13; ++j) o[j] = l[j] * inv;
    }
  } else {
    __shared__ float lz1[256], lz2[128], lz3[128], lz4[64], lzo[57 * 4];
    lz1[t] = z1g[m * 256 + t];
    __syncthreads();
    if (t < 128) {
      float s = b_r2[t];
      for (int k = 0; k < 256; ++k) s = fmaf(lz1[k], w_r2[k * 128 + t], s);
      lz2[t] = s > 0.f ? s : ALPHA * s;
    }
    __syncthreads();
    if (t < 128) {
      float s = b_r3[t];
      for (int k = 0; k < 128; ++k) s = fmaf(lz2[k], w_r3[k * 128 + t], s);
      lz3[t] = s > 0.f ? s : ALPHA * s;
    }
    __syncthreads();
    if (t < 64) {
      float s = b_r4[t];
      for (int k = 0; k < 128; ++k) s = fmaf(lz3[k], w_r4[k * 64 + t], s);
      lz4[t] = s > 0.f ? s : ALPHA * s;
    }
    __syncthreads();
    int p0 = (tile - 8) * 57;
    int np = 225 - p0; if (np > 57) np = 57;
    int ncols = np * 4;
    for (int n = t; n < ncols; n += 256) {
      int col = p0 * 4 + n;
      float s = b_ro[col];
#pragma unroll
      for (int k = 0; k < 64; ++k) s = fmaf(lz4[k], w_ro[k * 900 + col], s);
      lzo[n] = s;
    }
    __syncthreads();
    if (t < np) {
      float z[4];
#pragma unroll
      for (int i = 0; i < 4; ++i) z[i] = lzo[t * 4 + i];
      float* ro = reg_out + ((size_t)m * 225 + p0 + t) * 4;
#pragma unroll
      for (int j = 0; j < 4; ++j) {
        float s = b_sg[j];
#pragma unroll
        for (int i = 0; i < 4; ++i) s = fmaf(z[i], w_sg[i * 4 + j], s);
        ro[j] = 1.f / (1.f + expf(-s));
      }
    }
  }
}

// ---------------- workspace layout (bytes) ----------------
#define OFF_P1     ((size_t)0)            // 25,229,312
#define OFF_BPACK  ((size_t)25229312)     // 36,864
#define OFF_H      ((size_t)25266176)     // 11,935,744 (bf16 h)
#define OFF_PART1  ((size_t)37201920)     // 365*16448*4 = 24,014,080
#define OFF_PART2  ((size_t)61216000)     // 365*8256*4  = 12,053,760
#define OFF_Y1     ((size_t)73269760)     // 65,536
#define OFF_Z1     ((size_t)73335296)     // 32,768

extern "C" void kernel_launch(void* const* d_in, const int* in_sizes, int n_in,
                              void* d_out, int out_size, void* d_ws, size_t ws_size,
                              hipStream_t stream) {
  const float* x     = (const float*)d_in[0];
  const float* w1    = (const float*)d_in[1];
  const float* b1    = (const float*)d_in[2];
  const float* w2    = (const float*)d_in[3];
  const float* b2    = (const float*)d_in[4];
  const float* w_c1  = (const float*)d_in[5];
  const float* b_c1  = (const float*)d_in[6];
  const float* w_c2  = (const float*)d_in[7];
  const float* b_c2  = (const float*)d_in[8];
  const float* w_co  = (const float*)d_in[9];
  const float* b_co  = (const float*)d_in[10];
  const float* w_sm  = (const float*)d_in[11];
  const float* b_sm  = (const float*)d_in[12];
  const float* w_r1  = (const float*)d_in[13];
  const float* b_r1  = (const float*)d_in[14];
  const float* w_r2  = (const float*)d_in[15];
  const float* b_r2  = (const float*)d_in[16];
  const float* w_r3  = (const float*)d_in[17];
  const float* b_r3  = (const float*)d_in[18];
  const float* w_r4  = (const float*)d_in[19];
  const float* b_r4  = (const float*)d_in[20];
  const float* w_ro  = (const float*)d_in[21];
  const float* b_ro  = (const float*)d_in[22];
  const float* w_sg  = (const float*)d_in[23];
  const float* b_sg  = (const float*)d_in[24];

  char* ws = (char*)d_ws;
  unsigned short* p1    = (unsigned short*)(ws + OFF_P1);
  unsigned short* bpack = (unsigned short*)(ws + OFF_BPACK);
  unsigned short* hbf   = (unsigned short*)(ws + OFF_H);
  float*          part1 = (float*)(ws + OFF_PART1);
  float*          part2 = (float*)(ws + OFF_PART2);
  float*          y1    = (float*)(ws + OFF_Y1);
  float*          z1    = (float*)(ws + OFF_Z1);

  float* class_out = (float*)d_out;
  float* reg_out   = (float*)d_out + 32 * 225 * 13;

  conv1_pool<<<CONV1_BLOCKS + 72, 256, 0, stream>>>(x, w1, b1, p1, w2, bpack);
  conv2_pool<<<dim3(47, 32), 256, 0, stream>>>(p1, bpack, b2, hbf);
  gemm_mfma<<<dim3(3, NGK), 256, 0, stream>>>(w_c1, w_r1, hbf, part1, part2);
  reduce_big<<<768, 256, 0, stream>>>(part1, part2, b_c1, b_r1, y1, z1);
  tail_all<<<dim3(12, 32), 256, 0, stream>>>(y1, z1,
      w_c2, b_c2, w_co, b_co, w_sm, b_sm,
      w_r2, b_r2, w_r3, b_r3, w_r4, b_r4,
      w_ro, b_ro, w_sg, b_sg, class_out, reg_out);
}